// Round 4
// baseline (448.809 us; speedup 1.0000x reference)
//
#include <hip/hip_runtime.h>
#include <hip/hip_bf16.h>
#include <stdint.h>

#define D_IN  4096
#define D_OUT 4096
#define MROWS 8192   // 2 * 4096 rows of x

using i32x4 = __attribute__((ext_vector_type(4))) int;

// -------- Kernel 1 (fused): RMSNorm -> i8 xn (per-row absmax scale)
//          AND w_q fp32 -> i8 (exact, values in {-1,0,1}) ------------------
__global__ __launch_bounds__(256) void prep_kernel(
    const float* __restrict__ x, const float* __restrict__ nw,
    signed char* __restrict__ xq, float* __restrict__ srow,
    const float* __restrict__ wq, signed char* __restrict__ wb) {
  const int b = blockIdx.x;
  const int t = threadIdx.x;

  if (b < MROWS) {
    const float4* xr  = (const float4*)(x + (size_t)b * D_IN);
    const float4* nw4 = (const float4*)nw;

    float4 p[4];
    float ss = 0.f, mx = 0.f;
#pragma unroll
    for (int i = 0; i < 4; ++i) {
      const float4 v = xr[i * 256 + t];
      const float4 w = nw4[i * 256 + t];
      ss += v.x * v.x + v.y * v.y + v.z * v.z + v.w * v.w;
      p[i].x = v.x * w.x; p[i].y = v.y * w.y;
      p[i].z = v.z * w.z; p[i].w = v.w * w.w;
      mx = fmaxf(mx, fmaxf(fmaxf(fabsf(p[i].x), fabsf(p[i].y)),
                           fmaxf(fabsf(p[i].z), fabsf(p[i].w))));
    }
#pragma unroll
    for (int off = 32; off > 0; off >>= 1) {
      ss += __shfl_down(ss, off, 64);
      mx = fmaxf(mx, __shfl_down(mx, off, 64));
    }

    __shared__ float rs[4], rm[4];
    if ((t & 63) == 0) { rs[t >> 6] = ss; rm[t >> 6] = mx; }
    __syncthreads();
    const float scale =
        rsqrtf((rs[0] + rs[1] + rs[2] + rs[3]) * (1.0f / D_IN) + 1e-6f);
    const float rowmax = fmaxf(fmaxf(rm[0], rm[1]), fmaxf(rm[2], rm[3])) * scale;
    const float s   = fmaxf(rowmax, 1e-20f) * (1.0f / 127.0f);
    const float f   = scale / s;   // = scale * 127 / rowmax
    if (t == 0) srow[b] = s;

    int* out = (int*)(xq + (size_t)b * D_IN);
#pragma unroll
    for (int i = 0; i < 4; ++i) {
      const int q0 = (int)rintf(p[i].x * f);
      const int q1 = (int)rintf(p[i].y * f);
      const int q2 = (int)rintf(p[i].z * f);
      const int q3 = (int)rintf(p[i].w * f);
      out[i * 256 + t] =
          (q0 & 0xFF) | ((q1 & 0xFF) << 8) | ((q2 & 0xFF) << 16) | (q3 << 24);
    }
  } else {
    const int cb = b - MROWS;
    const float4* w4 = (const float4*)wq;
    int* o = (int*)wb;
#pragma unroll
    for (int i = 0; i < 4; ++i) {
      const int idx = cb * 1024 + i * 256 + t;
      const float4 v = w4[idx];
      const int q0 = (int)v.x, q1 = (int)v.y, q2 = (int)v.z, q3 = (int)v.w;
      o[idx] = (q0 & 0xFF) | ((q1 & 0xFF) << 8) | ((q2 & 0xFF) << 16) | (q3 << 24);
    }
  }
}

// ---------------- Kernel 2: i8 GEMM (A: MxK, B: NxK i.e. B^T) -------------
// mfma_i32_16x16x64_i8: per lane A[m=lane&15][k=(lane>>4)*16 + j], j in [0,16).
// C/D layout (shape-determined): col=lane&15, row=(lane>>4)*4+reg.
//
// R4 STRUCTURE (post-mortems R2/R3: barrier count AND prefetch depth matter,
// but the real co-bottleneck was LDS port traffic ~= MFMA cycles):
//   R1 skeleton: 256x256 tile, 8 waves (2Mx4N, wave 128x64), BKB=64,
//   4-deep LDS ring for A ONLY (4 x 16 KB = 64 KB), 1 barrier per K-tile.
//   B fragments are loaded GLOBAL->REGISTER one K-tile ahead (bf0/bf1
//   ping-pong, named arrays - no runtime indexing). This removes 48 KB of
//   LDS traffic per K-tile (B frag reads 32 KB + B DMA writes 16 KB):
//   LDS/tile = 80 KB (~625 cyc) < MFMA/tile (~1300 cyc) -> MFMA-bound.
//   B redundancy is 2x from global, but per-XCD the B working set is
//   bn in {x, x+8} = 2 MB < 4 MB L2 -> L2-hot (~10 TB/s << 34.5 ceiling).
//   No manual vmcnt in the main loop: bfC are VGPR loads, so the compiler
//   emits the counted vmcnt(N) itself; A(T+1)'s gload_lds (issued body T-2)
//   is strictly older than bf(T)'s loads (body T-1), so that wait + barrier
//   also proves the next A slot has landed.
//
// A LDS swizzle unchanged (proven 0 conflicts): 16B chunk (row, j) at slot
// j ^ ((row>>1)&3), applied on the global source, compensated in ds_read.
#define BM 256
#define BN 256
#define BKB 64                  // K bytes per tile == one MFMA k-step
#define NKT (D_IN / BKB)        // 64 K-tiles
#define SLOT_BYTES (BM * BKB)   // 16 KB per ring slot

#define WVM(n_) asm volatile("s_waitcnt vmcnt(" #n_ ")" ::: "memory")

// Stage A half-tile rows for tile t_ into ring slot t_&3 (2 x gload_lds).
#define STAGEA(t_)                                                            \
  do {                                                                        \
    _Pragma("unroll") for (int _i = 0; _i < 2; ++_i)                          \
        __builtin_amdgcn_global_load_lds(                                     \
            (__attribute__((address_space(1))) void*)(A + aOff[_i] +          \
                                                      (t_) * BKB),            \
            (__attribute__((address_space(3))) void*)&sA[(t_) & 3]            \
                                                       [ldsOff[_i]],          \
            16, 0, 0);                                                        \
  } while (0)

// Load B fragments for tile t_ into register array bf_ (4 x dwordx4).
#define LOADB(t_, bf_)                                                        \
  do {                                                                        \
    _Pragma("unroll") for (int _j = 0; _j < 4; ++_j)                          \
        bf_[_j] = *(const i32x4*)(Bp[_j] + (t_) * BKB);                       \
  } while (0)

// One K-tile body: ds_read A frags (slot T&3), issue next-B + future-A,
// 32 MFMA against bfC_, barrier.
#define BODY(T_, bfC_, LDB_, STG_)                                            \
  do {                                                                        \
    i32x4 af[8];                                                              \
    _Pragma("unroll") for (int _i = 0; _i < 8; ++_i)                          \
        af[_i] = *(const i32x4*)&sA[(T_) & 3][aoff0 + _i * (16 * BKB)];       \
    LDB_;                                                                     \
    STG_;                                                                     \
    __builtin_amdgcn_s_setprio(1);                                            \
    _Pragma("unroll") for (int _i = 0; _i < 8; ++_i)                          \
        _Pragma("unroll") for (int _j = 0; _j < 4; ++_j)                      \
            acc[_i][_j] = __builtin_amdgcn_mfma_i32_16x16x64_i8(              \
                af[_i], bfC_[_j], acc[_i][_j], 0, 0, 0);                      \
    __builtin_amdgcn_s_setprio(0);                                            \
    __builtin_amdgcn_s_barrier();                                             \
  } while (0)

__global__ __launch_bounds__(512, 2) void gemm_kernel(
    const signed char* __restrict__ A,   // MROWS x D_IN i8
    const signed char* __restrict__ B,   // D_OUT x D_IN i8
    const float* __restrict__ srow,      // MROWS   (per-row dequant scale)
    const float* __restrict__ gamma,     // D_OUT
    float* __restrict__ C) {             // MROWS x D_OUT fp32
  __shared__ __align__(16) signed char sA[4][SLOT_BYTES];  // 64 KB

  const int tid  = threadIdx.x;
  const int lane = tid & 63;
  const int wv   = tid >> 6;     // 0..7
  const int wm   = wv >> 2;      // 0..1: 128-row half of the 256-row tile
  const int wn   = wv & 3;       // 0..3: 64-col quarter of the 256-col tile
  const int bn   = blockIdx.x;   // 0..15
  const int bm   = blockIdx.y;   // 0..31

  i32x4 acc[8][4];
#pragma unroll
  for (int i = 0; i < 8; ++i)
#pragma unroll
    for (int j = 0; j < 4; ++j) acc[i][j] = (i32x4){0, 0, 0, 0};

  // A staging map (proven): per tile 1024 chunks of 16B; chunk c = i*512+tid
  // -> tile row r = c>>2, swizzled k-offset ((c&3) ^ ((r>>1)&3)) * 16.
  size_t aOff[2];
  int ldsOff[2];
#pragma unroll
  for (int i = 0; i < 2; ++i) {
    const int c  = i * 512 + tid;
    const int r  = c >> 2;
    const int cc = ((c & 3) ^ ((r >> 1) & 3)) * 16;
    aOff[i] = (size_t)(bm * BM + r) * D_IN + cc;
    ldsOff[i] = (i * 512 + wv * 64) * 16;  // wave-uniform base; +lane*16 by HW
  }

  // A fragment read offsets (swizzle-compensated).
  const int kk    = (((lane >> 4) ^ ((lane >> 1) & 3))) * 16;
  const int aoff0 = (wm * 128 + (lane & 15)) * BKB + kk;

  // B per-lane fragment base pointers: row = bn*256 + wn*64 + (lane&15) + j*16,
  // k-chunk (lane>>4)*16. Per-tile offset t*64 <= 4032 folds into the imm.
  const signed char* Bp[4];
#pragma unroll
  for (int j = 0; j < 4; ++j)
    Bp[j] = B + (size_t)(bn * BN + wn * 64 + (lane & 15) + j * 16) * D_IN +
            (lane >> 4) * 16;

  i32x4 bf0[4], bf1[4];

  // Prologue: stage A tiles 0..2, load B tile 0; wait for A0 only
  // (A1,A2,B0 = 8 ops stay in flight; compiler waits B0 before first MFMA).
  STAGEA(0); STAGEA(1); STAGEA(2);
  LOADB(0, bf0);
  WVM(8);
  __builtin_amdgcn_s_barrier();

  // Main loop (2-body unroll for bf ping-pong): body T computes tile T,
  // loads B(T+1), stages A(T+3).
#pragma unroll 1
  for (int TT = 0; TT < NKT - 4; TT += 2) {
    BODY(TT,     bf0, LOADB(TT + 1, bf1), STAGEA(TT + 3));
    BODY(TT + 1, bf1, LOADB(TT + 2, bf0), STAGEA(TT + 4));
  }
  // Tail: T = 60..63 (A staged through 62 by the loop; B loaded through 60).
  BODY(60, bf0, LOADB(61, bf1), STAGEA(63));
  BODY(61, bf1, LOADB(62, bf0), );
  BODY(62, bf0, LOADB(63, bf1), );
  {  // T = 63, no barrier
    i32x4 af[8];
#pragma unroll
    for (int i = 0; i < 8; ++i)
      af[i] = *(const i32x4*)&sA[63 & 3][aoff0 + i * (16 * BKB)];
#pragma unroll
    for (int i = 0; i < 8; ++i)
#pragma unroll
      for (int j = 0; j < 4; ++j)
        acc[i][j] = __builtin_amdgcn_mfma_i32_16x16x64_i8(
            af[i], bf1[j], acc[i][j], 0, 0, 0);
  }

  // Epilogue: y = acc * srow[row] * gamma[col]
  const int col0 = bn * BN + wn * 64 + (lane & 15);
  const int row0 = bm * BM + wm * 128 + ((lane >> 4) * 4);
  float g[4];
#pragma unroll
  for (int j = 0; j < 4; ++j) g[j] = gamma[col0 + j * 16];

#pragma unroll
  for (int i = 0; i < 8; ++i) {
#pragma unroll
    for (int r = 0; r < 4; ++r) {
      const int row = row0 + i * 16 + r;
      const float sr = srow[row];
#pragma unroll
      for (int j = 0; j < 4; ++j) {
        C[(size_t)row * D_OUT + col0 + j * 16] =
            (float)acc[i][j][r] * sr * g[j];
      }
    }
  }
}

#undef BODY
#undef LOADB
#undef STAGEA
#undef WVM

extern "C" void kernel_launch(void* const* d_in, const int* in_sizes, int n_in,
                              void* d_out, int out_size, void* d_ws, size_t ws_size,
                              hipStream_t stream) {
  const float* x     = (const float*)d_in[0];  // (2,4096,4096)
  const float* nw    = (const float*)d_in[1];  // (4096,)
  const float* wq    = (const float*)d_in[2];  // (4096,4096) {-1,0,1}
  const float* gamma = (const float*)d_in[3];  // (4096,)
  float* y = (float*)d_out;

  // Workspace: xq i8 (32 MB) | wb i8 (16 MB) | srow fp32 (32 KB)
  signed char* xq = (signed char*)d_ws;
  signed char* wb = xq + (size_t)MROWS * D_IN;
  float* srow = (float*)(wb + (size_t)D_OUT * D_IN);

  prep_kernel<<<MROWS + 4096, 256, 0, stream>>>(x, nw, xq, srow, wq, wb);

  gemm_kernel<<<dim3(D_OUT / BN, MROWS / BM), 512, 0, stream>>>(xq, wb, srow, gamma, y);
}

// Round 5
// 384.170 us; speedup vs baseline: 1.1683x; 1.1683x over previous
//
#include <hip/hip_runtime.h>
#include <hip/hip_bf16.h>
#include <stdint.h>

#define D_IN  4096
#define D_OUT 4096
#define MROWS 8192   // 2 * 4096 rows of x

using i32x4 = __attribute__((ext_vector_type(4))) int;

// -------- Kernel 1 (fused): RMSNorm -> i8 xn (per-row absmax scale)
//          AND w_q fp32 -> i8 (exact, values in {-1,0,1}) ------------------
__global__ __launch_bounds__(256) void prep_kernel(
    const float* __restrict__ x, const float* __restrict__ nw,
    signed char* __restrict__ xq, float* __restrict__ srow,
    const float* __restrict__ wq, signed char* __restrict__ wb) {
  const int b = blockIdx.x;
  const int t = threadIdx.x;

  if (b < MROWS) {
    const float4* xr  = (const float4*)(x + (size_t)b * D_IN);
    const float4* nw4 = (const float4*)nw;

    float4 p[4];
    float ss = 0.f, mx = 0.f;
#pragma unroll
    for (int i = 0; i < 4; ++i) {
      const float4 v = xr[i * 256 + t];
      const float4 w = nw4[i * 256 + t];
      ss += v.x * v.x + v.y * v.y + v.z * v.z + v.w * v.w;
      p[i].x = v.x * w.x; p[i].y = v.y * w.y;
      p[i].z = v.z * w.z; p[i].w = v.w * w.w;
      mx = fmaxf(mx, fmaxf(fmaxf(fabsf(p[i].x), fabsf(p[i].y)),
                           fmaxf(fabsf(p[i].z), fabsf(p[i].w))));
    }
#pragma unroll
    for (int off = 32; off > 0; off >>= 1) {
      ss += __shfl_down(ss, off, 64);
      mx = fmaxf(mx, __shfl_down(mx, off, 64));
    }

    __shared__ float rs[4], rm[4];
    if ((t & 63) == 0) { rs[t >> 6] = ss; rm[t >> 6] = mx; }
    __syncthreads();
    const float scale =
        rsqrtf((rs[0] + rs[1] + rs[2] + rs[3]) * (1.0f / D_IN) + 1e-6f);
    const float rowmax = fmaxf(fmaxf(rm[0], rm[1]), fmaxf(rm[2], rm[3])) * scale;
    const float s   = fmaxf(rowmax, 1e-20f) * (1.0f / 127.0f);
    const float f   = scale / s;   // = scale * 127 / rowmax
    if (t == 0) srow[b] = s;

    int* out = (int*)(xq + (size_t)b * D_IN);
#pragma unroll
    for (int i = 0; i < 4; ++i) {
      const int q0 = (int)rintf(p[i].x * f);
      const int q1 = (int)rintf(p[i].y * f);
      const int q2 = (int)rintf(p[i].z * f);
      const int q3 = (int)rintf(p[i].w * f);
      out[i * 256 + t] =
          (q0 & 0xFF) | ((q1 & 0xFF) << 8) | ((q2 & 0xFF) << 16) | (q3 << 24);
    }
  } else {
    const int cb = b - MROWS;
    const float4* w4 = (const float4*)wq;
    int* o = (int*)wb;
#pragma unroll
    for (int i = 0; i < 4; ++i) {
      const int idx = cb * 1024 + i * 256 + t;
      const float4 v = w4[idx];
      const int q0 = (int)v.x, q1 = (int)v.y, q2 = (int)v.z, q3 = (int)v.w;
      o[idx] = (q0 & 0xFF) | ((q1 & 0xFF) << 8) | ((q2 & 0xFF) << 16) | (q3 << 24);
    }
  }
}

// ---------------- Kernel 2: i8 GEMM (A: MxK, B: NxK i.e. B^T) -------------
// mfma_i32_16x16x64_i8: per lane A[m=lane&15][k=(lane>>4)*16 + j], j in [0,16).
// C/D layout (shape-determined): col=lane&15, row=(lane>>4)*4+reg.
// LDS XOR-swizzle (proven 0 conflicts): 16B chunk (row, j) lives at slot
// j ^ ((row>>1)&3); applied by permuting the *global source* chunk,
// compensated in the ds_read address.
//
// R5 STRUCTURE = R1 skeleton (proven 141us/42%) + register-level fragment
// double-buffer (the m201 pattern R2 mis-ported): body T reads tile T+1's
// fragments into the spare register set, then runs the 32-MFMA cluster on
// tile T's fragments loaded LAST body. The ds_reads have no same-body
// consumer -> compiler's fine-grained lgkmcnt lets MFMA issue immediately
// while the DS pipe prefetches -> the ~1300cyc MFMA and ~1200cyc LDS pipe
// loads overlap instead of alternating (R1's 2x gap).
//
// Schedule invariant at body-T start: tiles <= T+1 landed, tile T+2 in
// flight (4 ops). Body T: read(T+1); STAGE(T+3) [8 outstanding]; MFMA(T);
// vmcnt(4) -> T+2 landed; barrier (per-wave vmcnt + barrier = all waves'
// DMA visible). Never drains to 0 in the main loop. STAGE(T+3) overwrites
// slot (T-1)&3, last read in body T-2, drained two barriers earlier.
// Ping-pong uses named f0/f1 arrays, 2-body unroll (no runtime indexing).
#define BM 256
#define BN 256
#define BKB 64                  // K bytes per tile == one MFMA k-step
#define NKT (D_IN / BKB)        // 64 K-tiles
#define SLOT_BYTES (BM * BKB)   // 16 KB per ring slot per operand

#define WVM(n_) asm volatile("s_waitcnt vmcnt(" #n_ ")" ::: "memory")
#define BAR()   __builtin_amdgcn_s_barrier()

// Stage tile t_ (A+B, 2+2 global_load_lds, 16B/lane) into ring slot t_&3.
#define STAGE(t_)                                                             \
  do {                                                                        \
    _Pragma("unroll") for (int _i = 0; _i < 2; ++_i)                          \
        __builtin_amdgcn_global_load_lds(                                     \
            (__attribute__((address_space(1))) void*)(A + aOff[_i] +          \
                                                      (t_) * BKB),            \
            (__attribute__((address_space(3))) void*)&sA[(t_) & 3]            \
                                                       [ldsOff[_i]],          \
            16, 0, 0);                                                        \
    _Pragma("unroll") for (int _i = 0; _i < 2; ++_i)                          \
        __builtin_amdgcn_global_load_lds(                                     \
            (__attribute__((address_space(1))) void*)(B + bOff[_i] +          \
                                                      (t_) * BKB),            \
            (__attribute__((address_space(3))) void*)&sB[(t_) & 3]            \
                                                       [ldsOff[_i]],          \
            16, 0, 0);                                                        \
  } while (0)

// Read tile t_'s fragments from ring slot t_&3 into register arrays fa_/fb_.
#define READF(t_, fa_, fb_)                                                   \
  do {                                                                        \
    _Pragma("unroll") for (int _i = 0; _i < 8; ++_i)                          \
        fa_[_i] = *(const i32x4*)&sA[(t_) & 3][aoff0 + _i * (16 * BKB)];      \
    _Pragma("unroll") for (int _j = 0; _j < 4; ++_j)                          \
        fb_[_j] = *(const i32x4*)&sB[(t_) & 3][boff0 + _j * (16 * BKB)];      \
  } while (0)

// 32-MFMA cluster on register fragments fa_/fb_.
#define MFMA_C(fa_, fb_)                                                      \
  do {                                                                        \
    __builtin_amdgcn_s_setprio(1);                                            \
    _Pragma("unroll") for (int _i = 0; _i < 8; ++_i)                          \
        _Pragma("unroll") for (int _j = 0; _j < 4; ++_j)                      \
            acc[_i][_j] = __builtin_amdgcn_mfma_i32_16x16x64_i8(              \
                fa_[_i], fb_[_j], acc[_i][_j], 0, 0, 0);                      \
    __builtin_amdgcn_s_setprio(0);                                            \
  } while (0)

// Body T: prefetch tile T+1's fragments into fn*, stage, compute tile T
// from fc*, counted wait, barrier.
#define BODY(T_, fcA_, fcB_, fnA_, fnB_, STG_, WAIT_)                         \
  do {                                                                        \
    READF((T_) + 1, fnA_, fnB_);                                              \
    STG_;                                                                     \
    MFMA_C(fcA_, fcB_);                                                       \
    WAIT_;                                                                    \
    BAR();                                                                    \
  } while (0)

__global__ __launch_bounds__(512, 2) void gemm_kernel(
    const signed char* __restrict__ A,   // MROWS x D_IN i8
    const signed char* __restrict__ B,   // D_OUT x D_IN i8
    const float* __restrict__ srow,      // MROWS   (per-row dequant scale)
    const float* __restrict__ gamma,     // D_OUT
    float* __restrict__ C) {             // MROWS x D_OUT fp32
  __shared__ __align__(16) signed char sA[4][SLOT_BYTES];  // 64 KB
  __shared__ __align__(16) signed char sB[4][SLOT_BYTES];  // 64 KB

  const int tid  = threadIdx.x;
  const int lane = tid & 63;
  const int wv   = tid >> 6;     // 0..7
  const int wm   = wv >> 2;      // 0..1: 128-row half of the 256-row tile
  const int wn   = wv & 3;       // 0..3: 64-col quarter of the 256-col tile
  const int bn   = blockIdx.x;   // 0..15
  const int bm   = blockIdx.y;   // 0..31

  i32x4 acc[8][4];
#pragma unroll
  for (int i = 0; i < 8; ++i)
#pragma unroll
    for (int j = 0; j < 4; ++j) acc[i][j] = (i32x4){0, 0, 0, 0};

  // Staging map: per tile per operand 1024 chunks of 16B; chunk
  // c = i*512 + tid -> tile row r = c>>2, swizzled k-byte offset.
  size_t aOff[2], bOff[2];
  int ldsOff[2];
#pragma unroll
  for (int i = 0; i < 2; ++i) {
    const int c  = i * 512 + tid;
    const int r  = c >> 2;
    const int cc = ((c & 3) ^ ((r >> 1) & 3)) * 16;
    aOff[i] = (size_t)(bm * BM + r) * D_IN + cc;
    bOff[i] = (size_t)(bn * BN + r) * D_IN + cc;
    ldsOff[i] = (i * 512 + wv * 64) * 16;  // wave-uniform base; +lane*16 by HW
  }

  // Fragment read offsets (swizzle-compensated; row base is a multiple of
  // 16 so (row>>1)&3 == (lane>>1)&3).
  const int kk    = (((lane >> 4) ^ ((lane >> 1) & 3))) * 16;
  const int aoff0 = (wm * 128 + (lane & 15)) * BKB + kk;
  const int boff0 = (wn * 64  + (lane & 15)) * BKB + kk;

  i32x4 f0a[8], f0b[4], f1a[8], f1b[4];

  // Prologue: stage tiles 0..2; vmcnt(4) lands tiles 0 AND 1 (tile 2's 4
  // ops stay in flight); barrier; preload tile 0's fragments.
  STAGE(0); STAGE(1); STAGE(2);
  WVM(4);
  BAR();
  READF(0, f0a, f0b);

  // Main loop, 2-body unroll for the f0/f1 ping-pong. Bodies 0..59.
#pragma unroll 1
  for (int T = 0; T < NKT - 4; T += 2) {
    BODY(T,     f0a, f0b, f1a, f1b, STAGE(T + 3), WVM(4));
    BODY(T + 1, f1a, f1b, f0a, f0b, STAGE(T + 4), WVM(4));
  }
  // Tail: bodies 60..63 (stages issued through 62 by the loop).
  BODY(60, f0a, f0b, f1a, f1b, STAGE(63), WVM(4));
  BODY(61, f1a, f1b, f0a, f0b, ,          WVM(0));   // tile 63 lands here
  // Body 62: read 63 into f1, compute 62; no more DMA -> no wait/barrier.
  READF(63, f1a, f1b);
  MFMA_C(f0a, f0b);
  // Body 63: compute last tile from registers.
  MFMA_C(f1a, f1b);

  // Epilogue: y = acc * srow[row] * gamma[col]
  const int col0 = bn * BN + wn * 64 + (lane & 15);
  const int row0 = bm * BM + wm * 128 + ((lane >> 4) * 4);
  float g[4];
#pragma unroll
  for (int j = 0; j < 4; ++j) g[j] = gamma[col0 + j * 16];

#pragma unroll
  for (int i = 0; i < 8; ++i) {
#pragma unroll
    for (int r = 0; r < 4; ++r) {
      const int row = row0 + i * 16 + r;
      const float sr = srow[row];
#pragma unroll
      for (int j = 0; j < 4; ++j) {
        C[(size_t)row * D_OUT + col0 + j * 16] =
            (float)acc[i][j][r] * sr * g[j];
      }
    }
  }
}

#undef BODY
#undef MFMA_C
#undef READF
#undef STAGE
#undef WVM
#undef BAR

extern "C" void kernel_launch(void* const* d_in, const int* in_sizes, int n_in,
                              void* d_out, int out_size, void* d_ws, size_t ws_size,
                              hipStream_t stream) {
  const float* x     = (const float*)d_in[0];  // (2,4096,4096)
  const float* nw    = (const float*)d_in[1];  // (4096,)
  const float* wq    = (const float*)d_in[2];  // (4096,4096) {-1,0,1}
  const float* gamma = (const float*)d_in[3];  // (4096,)
  float* y = (float*)d_out;

  // Workspace: xq i8 (32 MB) | wb i8 (16 MB) | srow fp32 (32 KB)
  signed char* xq = (signed char*)d_ws;
  signed char* wb = xq + (size_t)MROWS * D_IN;
  float* srow = (float*)(wb + (size_t)D_OUT * D_IN);

  prep_kernel<<<MROWS + 4096, 256, 0, stream>>>(x, nw, xq, srow, wq, wb);

  gemm_kernel<<<dim3(D_OUT / BN, MROWS / BM), 512, 0, stream>>>(xq, wb, srow, gamma, y);
}